// Round 5
// baseline (218.520 us; speedup 1.0000x reference)
//
#include <hip/hip_runtime.h>

#define CROPX 512
#define NN 510          // CROP - 2
#define BATCHX 32

constexpr float INV_DX   = 100.0f;     // 1/DX
constexpr float DT_F     = 0.001f;
constexpr float INV_DXDT = 100000.0f;  // 1/(DX*DT)
constexpr float INV_DX2  = 10000.0f;   // 1/DX^2

// Load 6 consecutive row elements per thread: aligned float4 + 2 halo scalars,
// all direct (no cross-lane on the load path). Clamped columns only affect
// lanes whose outputs are masked out.
__device__ __forceinline__ void load_row6(const float* __restrict__ base, int r,
                                          int c0, float o[6]) {
    const float* rp = base + (size_t)r * CROPX;
    const float4 q = *reinterpret_cast<const float4*>(rp + c0);
    int c4 = c0 + 4; if (c4 > CROPX - 1) c4 = CROPX - 1;
    int c5 = c0 + 5; if (c5 > CROPX - 1) c5 = CROPX - 1;
    float h0 = rp[c4];
    float h1 = rp[c5];
    o[0] = q.x; o[1] = q.y; o[2] = q.z; o[3] = q.w; o[4] = h0; o[5] = h1;
}

// -------------------- main interior kernel --------------------
// Wave = 64 lanes x 4 cols = 256 cols. Each wave owns an 8-row tile; rows
// stream with register carry. Depth-1 register double-buffer: iteration it
// computes from buffer CUR (row a+2) while buffer NXT (row a+3) is in flight.
__global__ __launch_bounds__(256, 4) void pde_main(const float* __restrict__ g,
                                                   const float* __restrict__ png,
                                                   float* __restrict__ ws) {
    const int bb   = blockIdx.z;
    const int w    = threadIdx.x >> 6;
    const int lane = threadIdx.x & 63;
    const int tile = blockIdx.y * 4 + w;       // 0..63
    const int cg   = blockIdx.x;               // 0..1
    const int c0   = cg * 256 + lane * 4;      // first owned col (16B aligned)
    const int a0   = tile * 8;                 // first output row

    const float* u  = g + (size_t)bb * 3 * (CROPX * CROPX);
    const float* v  = u + CROPX * CROPX;
    const float* p  = v + CROPX * CROPX;
    const float* pn = png + (size_t)bb * (CROPX * CROPX);

    const bool edgelane = (cg == 1 && lane == 0);   // col 256: left col in other cg

    float u1[6], v1[6], p1[6], pn1[6];              // row r1 = a+1 state
    float uA[6], vA[6], pA[6], pnA[6];              // row r2 buffer A
    float uB[6], vB[6], pB[6], pnB[6];              // row r2 buffer B
    float fnuC[5], fnvC[5], dvdtC[4], ppN[4], vup[4];
    float uLeftCur = 0.0f;

    // ---- warmup: issue ALL initial loads first (independent), then compute ----
    {
        float ua[6], va[6], pa[6], pna[6];
        load_row6(u,  a0, c0, ua);
        load_row6(v,  a0, c0, va);
        load_row6(p,  a0, c0, pa);
        load_row6(pn, a0, c0, pna);
        load_row6(u,  a0 + 1, c0, u1);
        load_row6(v,  a0 + 1, c0, v1);
        load_row6(p,  a0 + 1, c0, p1);
        load_row6(pn, a0 + 1, c0, pn1);
        load_row6(u,  a0 + 2, c0, uA);       // prefetch it=0's r2
        load_row6(v,  a0 + 2, c0, vA);
        load_row6(p,  a0 + 2, c0, pA);
        load_row6(pn, a0 + 2, c0, pnA);
        if (edgelane) uLeftCur = u[(size_t)(a0 + 1) * CROPX + (c0 - 1)];

        #pragma unroll
        for (int j = 0; j < 5; ++j)
            fnuC[j] = 0.5f * (va[j] + va[j + 1]) * 0.5f * (ua[j] + u1[j]) - (u1[j] - ua[j]);
        #pragma unroll
        for (int j = 1; j < 5; ++j) {
            float m = 0.5f * (va[j] + v1[j]);
            fnvC[j] = m * m - (v1[j] - va[j]);
        }
        #pragma unroll
        for (int k = 0; k < 4; ++k) { ppN[k] = pna[k + 1] - pa[k + 1]; vup[k] = va[k + 1]; }

        if (a0 > 0) {
            float vm[6];
            load_row6(v, a0 - 1, c0, vm);
            float fev[5];
            #pragma unroll
            for (int j = 0; j < 5; ++j)
                fev[j] = 0.5f * (ua[j] + u1[j]) * 0.5f * (va[j] + va[j + 1]) - (va[j + 1] - va[j]);
            #pragma unroll
            for (int k = 0; k < 4; ++k) {
                float mm = 0.5f * (vm[k + 1] + va[k + 1]);
                float fnvm = mm * mm - (va[k + 1] - vm[k + 1]);
                dvdtC[k] = (-(fev[k + 1] - fev[k]) - (fnvC[k + 1] - fnvm)
                            - (p1[k + 1] - pa[k + 1])) * INV_DX;
            }
        } else {
            #pragma unroll
            for (int k = 0; k < 4; ++k) dvdtC[k] = 0.0f;
        }
    }

    float cont_acc = 0.0f, pois_acc = 0.0f;

// One pipeline stage: compute from (uC..) = row a+2, prefetch (uN..) = row a+3.
#define PDE_BODY(IT, uC, vC, pC, pnC, uN, vN, pN, pnN)                              \
    {                                                                               \
        const int a   = a0 + (IT);                                                  \
        const int r1  = (a + 1 < CROPX) ? a + 1 : CROPX - 1;                        \
        const int r2n = (a + 3 < CROPX) ? a + 3 : CROPX - 1;                        \
        float uLeftNxt = 0.0f;                                                      \
        if ((IT) < 7) {                                                             \
            load_row6(u,  r2n, c0, uN);                                             \
            load_row6(v,  r2n, c0, vN);                                             \
            load_row6(p,  r2n, c0, pN);                                             \
            load_row6(pn, r2n, c0, pnN);                                            \
        }                                                                           \
        if (edgelane) uLeftNxt = u[(size_t)((a + 2 < CROPX) ? a + 2 : CROPX - 1)    \
                                   * CROPX + (c0 - 1)];                             \
        float FEu[5], FEv[5], FNu1[5], FNv1[5];                                     \
        _Pragma("unroll")                                                           \
        for (int j = 0; j < 5; ++j) {                                               \
            float ux = 0.5f * (u1[j] + u1[j + 1]);                                  \
            FEu[j] = ux * ux - (u1[j + 1] - u1[j]);                                 \
            float uy = 0.5f * (u1[j] + uC[j]);                                      \
            float vx = 0.5f * (v1[j] + v1[j + 1]);                                  \
            float prod = uy * vx;                                                   \
            FEv[j]  = prod - (v1[j + 1] - v1[j]);                                   \
            FNu1[j] = prod - (uC[j] - u1[j]);                                       \
        }                                                                           \
        _Pragma("unroll")                                                           \
        for (int j = 1; j < 5; ++j) {                                               \
            float vy = 0.5f * (v1[j] + vC[j]);                                      \
            FNv1[j] = vy * vy - (vC[j] - v1[j]);                                    \
        }                                                                           \
        float dudt[4], dvdt[4];                                                     \
        _Pragma("unroll")                                                           \
        for (int k = 0; k < 4; ++k) {                                               \
            dudt[k] = (-(FEu[k + 1] - FEu[k]) - (FNu1[k + 1] - fnuC[k + 1])         \
                       - (p1[k + 2] - p1[k + 1])) * INV_DX;                         \
            dvdt[k] = (-(FEv[k + 1] - FEv[k]) - (FNv1[k + 1] - fnvC[k + 1])         \
                       - (pC[k + 1] - p1[k + 1])) * INV_DX;                         \
        }                                                                           \
        float dudtLm = __shfl_up(dudt[3], 1, 64);                                   \
        if (edgelane) {                                                             \
            float uxm  = 0.5f * (uLeftCur + u1[0]);                                 \
            float FEuL = uxm * uxm - (u1[0] - uLeftCur);                            \
            dudtLm = (-(FEu[0] - FEuL) - (FNu1[0] - fnuC[0])                        \
                      - (p1[1] - p1[0])) * INV_DX;                                  \
        }                                                                           \
        _Pragma("unroll")                                                           \
        for (int k = 0; k < 4; ++k) {                                               \
            const int b = c0 + k;                                                   \
            float ppC = pn1[k + 1] - p1[k + 1];                                     \
            float ppS = pnC[k + 1] - pC[k + 1];                                     \
            float ppW = pn1[k]     - p1[k];                                         \
            float ppE = pn1[k + 2] - p1[k + 2];                                     \
            float lap = 4.0f * ppC - ppE - ppW - ppS - ppN[k];                      \
            float du_x = u1[k + 1] - u1[k];                                         \
            float dv_y = v1[k + 1] - vup[k];                                        \
            float dL  = (k == 0) ? dudtLm : dudt[k - 1];                            \
            float dRm = (b <= NN - 2) ? dudt[k] : 0.0f;                             \
            float dLm = (b >= 1)      ? dL      : 0.0f;                             \
            float vCm = (a <= NN - 2) ? dvdt[k] : 0.0f;                             \
            float vPm = (a >= 1)      ? dvdtC[k] : 0.0f;                            \
            float bconv = (du_x + dv_y + DT_F * ((dRm - dLm) + (vCm - vPm)))        \
                          * INV_DXDT;                                               \
            float pois  = lap * INV_DX2 + bconv;                                    \
            if (b < NN && a < NN) {                                                 \
                cont_acc += fabsf((du_x + dv_y) * INV_DX);                          \
                pois_acc += fabsf(pois);                                            \
            }                                                                       \
            ppN[k]   = ppC;                                                         \
            vup[k]   = v1[k + 1];                                                   \
            dvdtC[k] = dvdt[k];                                                     \
        }                                                                           \
        _Pragma("unroll")                                                           \
        for (int j = 0; j < 5; ++j) { fnuC[j] = FNu1[j]; if (j >= 1) fnvC[j] = FNv1[j]; } \
        _Pragma("unroll")                                                           \
        for (int j = 0; j < 6; ++j) {                                               \
            u1[j] = uC[j]; v1[j] = vC[j]; p1[j] = pC[j]; pn1[j] = pnC[j];           \
        }                                                                           \
        uLeftCur = uLeftNxt;                                                        \
    }

    PDE_BODY(0, uA, vA, pA, pnA, uB, vB, pB, pnB)
    PDE_BODY(1, uB, vB, pB, pnB, uA, vA, pA, pnA)
    PDE_BODY(2, uA, vA, pA, pnA, uB, vB, pB, pnB)
    PDE_BODY(3, uB, vB, pB, pnB, uA, vA, pA, pnA)
    PDE_BODY(4, uA, vA, pA, pnA, uB, vB, pB, pnB)
    PDE_BODY(5, uB, vB, pB, pnB, uA, vA, pA, pnA)
    PDE_BODY(6, uA, vA, pA, pnA, uB, vB, pB, pnB)
    PDE_BODY(7, uB, vB, pB, pnB, uA, vA, pA, pnA)
#undef PDE_BODY

    // ---- wave + block reduction, one atomic per block ----
    float c = cont_acc, q = pois_acc;
    #pragma unroll
    for (int off = 32; off > 0; off >>= 1) {
        c += __shfl_down(c, off, 64);
        q += __shfl_down(q, off, 64);
    }
    __shared__ float sred[8];
    if (lane == 0) { sred[w] = c; sred[4 + w] = q; }
    __syncthreads();
    if (threadIdx.x == 0) {
        atomicAdd(&ws[0], sred[0] + sred[1] + sred[2] + sred[3]);
        atomicAdd(&ws[1], sred[4] + sred[5] + sred[6] + sred[7]);
    }
}

// -------------------- boundary-condition partial sums --------------------
__global__ __launch_bounds__(256) void pde_bc(const float* __restrict__ g,
                                              float* __restrict__ ws) {
    const int bb    = blockIdx.y;
    const int slice = blockIdx.x;          // 0..7
    const int lane  = threadIdx.x & 63;
    const int role  = threadIdx.x >> 6;    // 0:y0 1:yL 2:x0 3:xL (one wave each)
    const int j     = slice * 64 + lane;   // 0..511

    const float* u = g + (size_t)bb * 3 * (CROPX * CROPX);
    const float* v = u + CROPX * CROPX;
    const float* p = v + CROPX * CROPX;

    const bool in9  = (j >= 1 && j <= NN - 1);   // 1..509
    const bool in10 = (j >= 1 && j <= NN);       // 1..510

    float val = 0.0f;
    if (role == 0) {
        if (in9)  val += u[j] + u[CROPX + j];
        if (in10) val += v[j] + p[j];
    } else if (role == 1) {
        if (in9)  val += 2.0f - u[(size_t)NN * CROPX + j] - u[(size_t)(NN + 1) * CROPX + j];
        if (in10) val += v[(size_t)(NN + 1) * CROPX + j] + p[(size_t)(NN + 1) * CROPX + j];
    } else if (role == 2) {
        if (in9)  val += v[(size_t)j * CROPX] + v[(size_t)j * CROPX + 1];
        if (in10) val += u[(size_t)j * CROPX] + p[(size_t)j * CROPX];
    } else {
        if (in9)  val += v[(size_t)j * CROPX + (CROPX - 1)] + v[(size_t)j * CROPX + (CROPX - 2)];
        if (in10) val += u[(size_t)j * CROPX + (CROPX - 1)] + p[(size_t)j * CROPX + (CROPX - 1)];
    }

    #pragma unroll
    for (int off = 32; off > 0; off >>= 1) val += __shfl_down(val, off, 64);
    if (lane == 0) atomicAdd(&ws[4 + bb * 4 + role], val);
}

// -------------------- final combine --------------------
__global__ void pde_final(const float* __restrict__ ws, float* __restrict__ out) {
    const int t = threadIdx.x;   // 64 threads
    float bc = 0.0f;
    if (t < BATCHX) {
        const float* wb = ws + 4 + t * 4;
        bc = fabsf(wb[0]) + fabsf(wb[1]) + fabsf(wb[2]) + fabsf(wb[3]);
    }
    #pragma unroll
    for (int off = 32; off > 0; off >>= 1) bc += __shfl_down(bc, off, 64);
    if (t == 0) {
        const float inv = 1.0f / ((float)BATCHX * NN * NN);
        out[0] = 0.4f * (ws[0] + ws[1]) * inv + 0.2f * bc;
    }
}

extern "C" void kernel_launch(void* const* d_in, const int* in_sizes, int n_in,
                              void* d_out, int out_size, void* d_ws, size_t ws_size,
                              hipStream_t stream) {
    const float* g  = (const float*)d_in[0];   // gen_output (32,3,512,512) f32
    const float* pn = (const float*)d_in[1];   // p_next_step (32,1,512,512) f32
    float* out = (float*)d_out;
    float* ws  = (float*)d_ws;

    hipMemsetAsync(ws, 0, (4 + BATCHX * 4) * sizeof(float), stream);

    dim3 gm(2, 16, 32);   // colgroup, supertile(4 waves of row-tiles), batch
    pde_main<<<gm, 256, 0, stream>>>(g, pn, ws);
    dim3 gb(8, 32);       // j-slice, batch
    pde_bc<<<gb, 256, 0, stream>>>(g, ws);
    pde_final<<<1, 64, 0, stream>>>(ws, out);
}

// Round 6
// 214.067 us; speedup vs baseline: 1.0208x; 1.0208x over previous
//
#include <hip/hip_runtime.h>

#define CROPX 512
#define NN 510          // CROP - 2
#define BATCHX 32

constexpr float INV_DX   = 100.0f;     // 1/DX
constexpr float DT_F     = 0.001f;
constexpr float INV_DXDT = 100000.0f;  // 1/(DX*DT)
constexpr float INV_DX2  = 10000.0f;   // 1/DX^2

// Load 6 consecutive row elements per thread: aligned float4 + float2 halo
// (two clamped scalars only on the last lane of the grid edge). All direct,
// no cross-lane on the load path -> loads stay mutually independent.
__device__ __forceinline__ void load_row6(const float* __restrict__ base, int r,
                                          int c0, float o[6]) {
    const float* rp = base + (size_t)r * CROPX;
    const float4 q = *reinterpret_cast<const float4*>(rp + c0);
    float h0, h1;
    if (c0 + 5 <= CROPX - 1) {                 // all lanes except col-508 lane
        const float2 h = *reinterpret_cast<const float2*>(rp + c0 + 4);
        h0 = h.x; h1 = h.y;
    } else {                                   // clamp (outputs there are masked)
        h0 = rp[CROPX - 1];
        h1 = rp[CROPX - 1];
    }
    o[0] = q.x; o[1] = q.y; o[2] = q.z; o[3] = q.w; o[4] = h0; o[5] = h1;
}

// -------------------- main interior kernel --------------------
// Wave = 64 lanes x 4 cols = 256 cols (cg picks which half). Each wave owns a
// 4-row tile (2048 blocks -> 32 waves/CU supply); rows stream with register
// carry (row r1 kept, row r2 loaded, single buffer -- R4 structure).
__global__ __launch_bounds__(256, 4) void pde_main(const float* __restrict__ g,
                                                   const float* __restrict__ png,
                                                   float* __restrict__ ws) {
    const int bb   = blockIdx.z;
    const int w    = threadIdx.x >> 6;
    const int lane = threadIdx.x & 63;
    const int tile = blockIdx.y * 4 + w;       // 0..127
    const int cg   = blockIdx.x;               // 0..1
    const int c0   = cg * 256 + lane * 4;      // first owned col (16B aligned)
    const int a0   = tile * 4;                 // first output row

    const float* u  = g + (size_t)bb * 3 * (CROPX * CROPX);
    const float* v  = u + CROPX * CROPX;
    const float* p  = v + CROPX * CROPX;
    const float* pn = png + (size_t)bb * (CROPX * CROPX);

    const bool edgelane = (cg == 1 && lane == 0);   // col 256: left col in other cg

    float u1[6], v1[6], p1[6], pn1[6];             // row r1 = a+1
    float fnuC[5], fnvC[5], dvdtC[4], ppN[4], vup[4];

    // ---- warmup: rows a0-1 (v only), a0, a0+1 ----
    {
        float ua[6], va[6], pa[6], pna[6];
        load_row6(u,  a0, c0, ua);
        load_row6(v,  a0, c0, va);
        load_row6(p,  a0, c0, pa);
        load_row6(pn, a0, c0, pna);
        load_row6(u,  a0 + 1, c0, u1);
        load_row6(v,  a0 + 1, c0, v1);
        load_row6(p,  a0 + 1, c0, p1);
        load_row6(pn, a0 + 1, c0, pn1);

        #pragma unroll
        for (int j = 0; j < 5; ++j)
            fnuC[j] = 0.5f * (va[j] + va[j + 1]) * 0.5f * (ua[j] + u1[j]) - (u1[j] - ua[j]);
        #pragma unroll
        for (int j = 1; j < 5; ++j) {
            float m = 0.5f * (va[j] + v1[j]);
            fnvC[j] = m * m - (v1[j] - va[j]);
        }
        #pragma unroll
        for (int k = 0; k < 4; ++k) { ppN[k] = pna[k + 1] - pa[k + 1]; vup[k] = va[k + 1]; }

        if (a0 > 0) {
            float vm[6];
            load_row6(v, a0 - 1, c0, vm);
            float fev[5];
            #pragma unroll
            for (int j = 0; j < 5; ++j)
                fev[j] = 0.5f * (ua[j] + u1[j]) * 0.5f * (va[j] + va[j + 1]) - (va[j + 1] - va[j]);
            #pragma unroll
            for (int k = 0; k < 4; ++k) {
                float mm = 0.5f * (vm[k + 1] + va[k + 1]);
                float fnvm = mm * mm - (va[k + 1] - vm[k + 1]);
                dvdtC[k] = (-(fev[k + 1] - fev[k]) - (fnvC[k + 1] - fnvm)
                            - (p1[k + 1] - pa[k + 1])) * INV_DX;
            }
        } else {
            #pragma unroll
            for (int k = 0; k < 4; ++k) dvdtC[k] = 0.0f;
        }
    }

    float cont_acc = 0.0f, pois_acc = 0.0f;

    #pragma unroll
    for (int it = 0; it < 4; ++it) {
        const int a  = a0 + it;
        const int r1 = (a + 1 < CROPX) ? a + 1 : CROPX - 1;   // clamp only on masked tail
        const int r2 = (a + 2 < CROPX) ? a + 2 : CROPX - 1;

        // ---- batch ALL loads for this iteration first (independent, no x-lane) ----
        float u2[6], v2[6], p2[6], pn2[6];
        load_row6(u,  r2, c0, u2);
        load_row6(v,  r2, c0, v2);
        load_row6(p,  r2, c0, p2);
        load_row6(pn, r2, c0, pn2);

        float uLeft = 0.0f;
        if (edgelane) uLeft = u[(size_t)r1 * CROPX + (c0 - 1)];

        // row-r1 fluxes at cols c0+j
        float FEu[5], FEv[5], FNu1[5], FNv1[5];
        #pragma unroll
        for (int j = 0; j < 5; ++j) {
            float ux = 0.5f * (u1[j] + u1[j + 1]);
            FEu[j] = ux * ux - (u1[j + 1] - u1[j]);
            float uy = 0.5f * (u1[j] + u2[j]);
            float vx = 0.5f * (v1[j] + v1[j + 1]);
            float prod = uy * vx;
            FEv[j]  = prod - (v1[j + 1] - v1[j]);
            FNu1[j] = prod - (u2[j] - u1[j]);
        }
        #pragma unroll
        for (int j = 1; j < 5; ++j) {
            float vy = 0.5f * (v1[j] + v2[j]);
            FNv1[j] = vy * vy - (v2[j] - v1[j]);
        }

        float dudt[4], dvdt[4];
        #pragma unroll
        for (int k = 0; k < 4; ++k) {
            dudt[k] = (-(FEu[k + 1] - FEu[k]) - (FNu1[k + 1] - fnuC[k + 1])
                       - (p1[k + 2] - p1[k + 1])) * INV_DX;
            dvdt[k] = (-(FEv[k + 1] - FEv[k]) - (FNv1[k + 1] - fnvC[k + 1])
                       - (p2[k + 1] - p1[k + 1])) * INV_DX;
        }

        // dudt(a, c0-1): from left lane; cg-boundary lane recomputes directly
        float dudtLm = __shfl_up(dudt[3], 1, 64);
        if (edgelane) {
            float uxm  = 0.5f * (uLeft + u1[0]);
            float FEuL = uxm * uxm - (u1[0] - uLeft);
            dudtLm = (-(FEu[0] - FEuL) - (FNu1[0] - fnuC[0]) - (p1[1] - p1[0])) * INV_DX;
        }

        #pragma unroll
        for (int k = 0; k < 4; ++k) {
            const int b = c0 + k;
            float ppC = pn1[k + 1] - p1[k + 1];
            float ppS = pn2[k + 1] - p2[k + 1];
            float ppW = pn1[k]     - p1[k];
            float ppE = pn1[k + 2] - p1[k + 2];
            float lap = 4.0f * ppC - ppE - ppW - ppS - ppN[k];
            float du_x = u1[k + 1] - u1[k];
            float dv_y = v1[k + 1] - vup[k];
            float dL  = (k == 0) ? dudtLm : dudt[k - 1];
            float dRm = (b <= NN - 2) ? dudt[k] : 0.0f;
            float dLm = (b >= 1)      ? dL      : 0.0f;
            float vCm = (a <= NN - 2) ? dvdt[k] : 0.0f;
            float vPm = (a >= 1)      ? dvdtC[k] : 0.0f;
            float bconv = (du_x + dv_y + DT_F * ((dRm - dLm) + (vCm - vPm))) * INV_DXDT;
            float pois  = lap * INV_DX2 + bconv;
            if (b < NN && a < NN) {
                cont_acc += fabsf((du_x + dv_y) * INV_DX);
                pois_acc += fabsf(pois);
            }
            ppN[k]   = ppC;          // becomes pp(a', b+1)
            vup[k]   = v1[k + 1];    // becomes v[a'][b+1]
            dvdtC[k] = dvdt[k];
        }
        #pragma unroll
        for (int j = 0; j < 5; ++j) { fnuC[j] = FNu1[j]; if (j >= 1) fnvC[j] = FNv1[j]; }
        #pragma unroll
        for (int j = 0; j < 6; ++j) { u1[j] = u2[j]; v1[j] = v2[j]; p1[j] = p2[j]; pn1[j] = pn2[j]; }
    }

    // ---- wave + block reduction, one atomic per block ----
    float c = cont_acc, q = pois_acc;
    #pragma unroll
    for (int off = 32; off > 0; off >>= 1) {
        c += __shfl_down(c, off, 64);
        q += __shfl_down(q, off, 64);
    }
    __shared__ float sred[8];
    if (lane == 0) { sred[w] = c; sred[4 + w] = q; }
    __syncthreads();
    if (threadIdx.x == 0) {
        atomicAdd(&ws[0], sred[0] + sred[1] + sred[2] + sred[3]);
        atomicAdd(&ws[1], sred[4] + sred[5] + sred[6] + sred[7]);
    }
}

// -------------------- boundary-condition partial sums --------------------
// Signed per-batch edge sums accumulate into ws[4 + 4*batch + role] from many
// blocks; abs() is deferred to pde_final (so no one-block-per-batch limit).
__global__ __launch_bounds__(256) void pde_bc(const float* __restrict__ g,
                                              float* __restrict__ ws) {
    const int bb    = blockIdx.y;
    const int slice = blockIdx.x;          // 0..7
    const int lane  = threadIdx.x & 63;
    const int role  = threadIdx.x >> 6;    // 0:y0 1:yL 2:x0 3:xL (one wave each)
    const int j     = slice * 64 + lane;   // 0..511

    const float* u = g + (size_t)bb * 3 * (CROPX * CROPX);
    const float* v = u + CROPX * CROPX;
    const float* p = v + CROPX * CROPX;

    const bool in9  = (j >= 1 && j <= NN - 1);   // 1..509
    const bool in10 = (j >= 1 && j <= NN);       // 1..510

    float val = 0.0f;
    if (role == 0) {
        if (in9)  val += u[j] + u[CROPX + j];
        if (in10) val += v[j] + p[j];
    } else if (role == 1) {
        if (in9)  val += 2.0f - u[(size_t)NN * CROPX + j] - u[(size_t)(NN + 1) * CROPX + j];
        if (in10) val += v[(size_t)(NN + 1) * CROPX + j] + p[(size_t)(NN + 1) * CROPX + j];
    } else if (role == 2) {
        if (in9)  val += v[(size_t)j * CROPX] + v[(size_t)j * CROPX + 1];
        if (in10) val += u[(size_t)j * CROPX] + p[(size_t)j * CROPX];
    } else {
        if (in9)  val += v[(size_t)j * CROPX + (CROPX - 1)] + v[(size_t)j * CROPX + (CROPX - 2)];
        if (in10) val += u[(size_t)j * CROPX + (CROPX - 1)] + p[(size_t)j * CROPX + (CROPX - 1)];
    }

    #pragma unroll
    for (int off = 32; off > 0; off >>= 1) val += __shfl_down(val, off, 64);
    if (lane == 0) atomicAdd(&ws[4 + bb * 4 + role], val);
}

// -------------------- final combine --------------------
__global__ void pde_final(const float* __restrict__ ws, float* __restrict__ out) {
    const int t = threadIdx.x;   // 64 threads
    float bc = 0.0f;
    if (t < BATCHX) {
        const float* wb = ws + 4 + t * 4;
        bc = fabsf(wb[0]) + fabsf(wb[1]) + fabsf(wb[2]) + fabsf(wb[3]);
    }
    #pragma unroll
    for (int off = 32; off > 0; off >>= 1) bc += __shfl_down(bc, off, 64);
    if (t == 0) {
        const float inv = 1.0f / ((float)BATCHX * NN * NN);
        out[0] = 0.4f * (ws[0] + ws[1]) * inv + 0.2f * bc;
    }
}

extern "C" void kernel_launch(void* const* d_in, const int* in_sizes, int n_in,
                              void* d_out, int out_size, void* d_ws, size_t ws_size,
                              hipStream_t stream) {
    const float* g  = (const float*)d_in[0];   // gen_output (32,3,512,512) f32
    const float* pn = (const float*)d_in[1];   // p_next_step (32,1,512,512) f32
    float* out = (float*)d_out;
    float* ws  = (float*)d_ws;

    hipMemsetAsync(ws, 0, (4 + BATCHX * 4) * sizeof(float), stream);

    dim3 gm(2, 32, 32);   // colgroup, supertile(4 waves of 4-row tiles), batch
    pde_main<<<gm, 256, 0, stream>>>(g, pn, ws);
    dim3 gb(8, 32);       // j-slice, batch
    pde_bc<<<gb, 256, 0, stream>>>(g, ws);
    pde_final<<<1, 64, 0, stream>>>(ws, out);
}

// Round 7
// 197.160 us; speedup vs baseline: 1.1083x; 1.0858x over previous
//
#include <hip/hip_runtime.h>

#define CROPX 512
#define NN 510          // CROP - 2
#define BATCHX 32

constexpr float INV_DX   = 100.0f;     // 1/DX
constexpr float DT_F     = 0.001f;
constexpr float INV_DXDT = 100000.0f;  // 1/(DX*DT)
constexpr float INV_DX2  = 10000.0f;   // 1/DX^2

__device__ __forceinline__ float4 ld4(const float* __restrict__ b, int r, int c) {
    return *reinterpret_cast<const float4*>(b + (size_t)r * CROPX + c);
}
__device__ __forceinline__ float2 ld2(const float* __restrict__ b, int r, int c) {
    return *reinterpret_cast<const float2*>(b + (size_t)r * CROPX + c);
}

// Expand own float4 to a 6-wide window using the RIGHT NEIGHBOR LANE's q.x/q.y
// (shfl_down). Called AFTER all loads of the iteration are issued, so the
// waits are batched (one latency per iteration, unlike R2's per-load chain).
// e63: cg0 lane63 -> halo comes from a masked float2 load (cols 256,257).
// c63: cg1 lane63 -> clamp to col 511 (== q.w); outputs there are masked.
__device__ __forceinline__ void extract6(float4 q, float2 h, bool e63, bool c63,
                                         float o[6]) {
    float h0 = __shfl_down(q.x, 1, 64);
    float h1 = __shfl_down(q.y, 1, 64);
    if (e63) { h0 = h.x; h1 = h.y; }
    if (c63) { h0 = q.w; h1 = q.w; }
    o[0] = q.x; o[1] = q.y; o[2] = q.z; o[3] = q.w; o[4] = h0; o[5] = h1;
}

// -------------------- main interior kernel --------------------
// Wave = 64 lanes x 4 cols = 256 cols (cg picks which half). 8-row tiles
// (R4 geometry, 16 waves/CU). Per iteration: exactly 4 full dwordx4 vmem
// instructions (fresh 1KB each) + masked single-lane edge loads; halo via
// post-batched shfl -> minimal TA-pipe pressure (the measured bottleneck).
__global__ __launch_bounds__(256, 4) void pde_main(const float* __restrict__ g,
                                                   const float* __restrict__ png,
                                                   float* __restrict__ ws) {
    const int bb   = blockIdx.z;
    const int w    = threadIdx.x >> 6;
    const int lane = threadIdx.x & 63;
    const int tile = blockIdx.y * 4 + w;       // 0..63
    const int cg   = blockIdx.x;               // 0..1
    const int c0   = cg * 256 + lane * 4;      // first owned col (16B aligned)
    const int a0   = tile * 8;                 // first output row

    const float* u  = g + (size_t)bb * 3 * (CROPX * CROPX);
    const float* v  = u + CROPX * CROPX;
    const float* p  = v + CROPX * CROPX;
    const float* pn = png + (size_t)bb * (CROPX * CROPX);

    const bool edge0   = (cg == 1 && lane == 0);    // needs uLeft (col 255)
    const bool edge63  = (cg == 0 && lane == 63);   // needs cols 256,257
    const bool clamp63 = (cg == 1 && lane == 63);   // c0 == 508: clamp

    float u1[6], v1[6], p1[6], pn1[6];             // row r1 = a+1
    float fnuC[5], fnvC[5], dvdtC[4], ppN[4], vup[4];

    // ---- warmup: rows a0-1 (v only), a0, a0+1 -- batch loads, then extract ----
    {
        const float2 z2 = make_float2(0.0f, 0.0f);
        float4 qua = ld4(u, a0, c0),     qva = ld4(v, a0, c0);
        float4 qpa = ld4(p, a0, c0),     qpna = ld4(pn, a0, c0);
        float4 qu1 = ld4(u, a0 + 1, c0), qv1 = ld4(v, a0 + 1, c0);
        float4 qp1 = ld4(p, a0 + 1, c0), qpn1 = ld4(pn, a0 + 1, c0);
        float4 qvm = make_float4(0.0f, 0.0f, 0.0f, 0.0f);
        if (a0 > 0) qvm = ld4(v, a0 - 1, c0);
        float2 hua = z2, hva = z2, hpa = z2, hpna = z2;
        float2 hu1 = z2, hv1 = z2, hp1 = z2, hpn1 = z2, hvm = z2;
        if (edge63) {
            hua = ld2(u, a0, 256);      hva = ld2(v, a0, 256);
            hpa = ld2(p, a0, 256);      hpna = ld2(pn, a0, 256);
            hu1 = ld2(u, a0 + 1, 256);  hv1 = ld2(v, a0 + 1, 256);
            hp1 = ld2(p, a0 + 1, 256);  hpn1 = ld2(pn, a0 + 1, 256);
            if (a0 > 0) hvm = ld2(v, a0 - 1, 256);
        }

        float ua[6], va[6], pa[6], pna[6], vm[6];
        extract6(qua, hua, edge63, clamp63, ua);
        extract6(qva, hva, edge63, clamp63, va);
        extract6(qpa, hpa, edge63, clamp63, pa);
        extract6(qpna, hpna, edge63, clamp63, pna);
        extract6(qu1, hu1, edge63, clamp63, u1);
        extract6(qv1, hv1, edge63, clamp63, v1);
        extract6(qp1, hp1, edge63, clamp63, p1);
        extract6(qpn1, hpn1, edge63, clamp63, pn1);
        extract6(qvm, hvm, edge63, clamp63, vm);

        #pragma unroll
        for (int j = 0; j < 5; ++j)
            fnuC[j] = 0.5f * (va[j] + va[j + 1]) * 0.5f * (ua[j] + u1[j]) - (u1[j] - ua[j]);
        #pragma unroll
        for (int j = 1; j < 5; ++j) {
            float m = 0.5f * (va[j] + v1[j]);
            fnvC[j] = m * m - (v1[j] - va[j]);
        }
        #pragma unroll
        for (int k = 0; k < 4; ++k) { ppN[k] = pna[k + 1] - pa[k + 1]; vup[k] = va[k + 1]; }

        if (a0 > 0) {
            float fev[5];
            #pragma unroll
            for (int j = 0; j < 5; ++j)
                fev[j] = 0.5f * (ua[j] + u1[j]) * 0.5f * (va[j] + va[j + 1]) - (va[j + 1] - va[j]);
            #pragma unroll
            for (int k = 0; k < 4; ++k) {
                float mm = 0.5f * (vm[k + 1] + va[k + 1]);
                float fnvm = mm * mm - (va[k + 1] - vm[k + 1]);
                dvdtC[k] = (-(fev[k + 1] - fev[k]) - (fnvC[k + 1] - fnvm)
                            - (p1[k + 1] - pa[k + 1])) * INV_DX;
            }
        } else {
            #pragma unroll
            for (int k = 0; k < 4; ++k) dvdtC[k] = 0.0f;
        }
    }

    float cont_acc = 0.0f, pois_acc = 0.0f;

    #pragma unroll
    for (int it = 0; it < 8; ++it) {
        const int a  = a0 + it;
        const int r1 = (a + 1 < CROPX) ? a + 1 : CROPX - 1;   // clamp only on masked tail
        const int r2 = (a + 2 < CROPX) ? a + 2 : CROPX - 1;

        // ---- batch ALL loads of this iteration, then extract (shfl after) ----
        const float2 z2 = make_float2(0.0f, 0.0f);
        float4 qu2 = ld4(u, r2, c0), qv2 = ld4(v, r2, c0);
        float4 qp2 = ld4(p, r2, c0), qpn2 = ld4(pn, r2, c0);
        float2 h2u = z2, h2v = z2, h2p = z2, h2pn = z2;
        if (edge63) {
            h2u = ld2(u, r2, 256);  h2v = ld2(v, r2, 256);
            h2p = ld2(p, r2, 256);  h2pn = ld2(pn, r2, 256);
        }
        float uLeft = 0.0f;
        if (edge0) uLeft = u[(size_t)r1 * CROPX + 255];

        float u2[6], v2[6], p2[6], pn2[6];
        extract6(qu2, h2u, edge63, clamp63, u2);
        extract6(qv2, h2v, edge63, clamp63, v2);
        extract6(qp2, h2p, edge63, clamp63, p2);
        extract6(qpn2, h2pn, edge63, clamp63, pn2);

        // row-r1 fluxes at cols c0+j
        float FEu[5], FEv[5], FNu1[5], FNv1[5];
        #pragma unroll
        for (int j = 0; j < 5; ++j) {
            float ux = 0.5f * (u1[j] + u1[j + 1]);
            FEu[j] = ux * ux - (u1[j + 1] - u1[j]);
            float uy = 0.5f * (u1[j] + u2[j]);
            float vx = 0.5f * (v1[j] + v1[j + 1]);
            float prod = uy * vx;
            FEv[j]  = prod - (v1[j + 1] - v1[j]);
            FNu1[j] = prod - (u2[j] - u1[j]);
        }
        #pragma unroll
        for (int j = 1; j < 5; ++j) {
            float vy = 0.5f * (v1[j] + v2[j]);
            FNv1[j] = vy * vy - (v2[j] - v1[j]);
        }

        float dudt[4], dvdt[4];
        #pragma unroll
        for (int k = 0; k < 4; ++k) {
            dudt[k] = (-(FEu[k + 1] - FEu[k]) - (FNu1[k + 1] - fnuC[k + 1])
                       - (p1[k + 2] - p1[k + 1])) * INV_DX;
            dvdt[k] = (-(FEv[k + 1] - FEv[k]) - (FNv1[k + 1] - fnvC[k + 1])
                       - (p2[k + 1] - p1[k + 1])) * INV_DX;
        }

        // dudt(a, c0-1): from left lane; cg-boundary lane recomputes directly
        float dudtLm = __shfl_up(dudt[3], 1, 64);
        if (edge0) {
            float uxm  = 0.5f * (uLeft + u1[0]);
            float FEuL = uxm * uxm - (u1[0] - uLeft);
            dudtLm = (-(FEu[0] - FEuL) - (FNu1[0] - fnuC[0]) - (p1[1] - p1[0])) * INV_DX;
        }

        #pragma unroll
        for (int k = 0; k < 4; ++k) {
            const int b = c0 + k;
            float ppC = pn1[k + 1] - p1[k + 1];
            float ppS = pn2[k + 1] - p2[k + 1];
            float ppW = pn1[k]     - p1[k];
            float ppE = pn1[k + 2] - p1[k + 2];
            float lap = 4.0f * ppC - ppE - ppW - ppS - ppN[k];
            float du_x = u1[k + 1] - u1[k];
            float dv_y = v1[k + 1] - vup[k];
            float dL  = (k == 0) ? dudtLm : dudt[k - 1];
            float dRm = (b <= NN - 2) ? dudt[k] : 0.0f;
            float dLm = (b >= 1)      ? dL      : 0.0f;
            float vCm = (a <= NN - 2) ? dvdt[k] : 0.0f;
            float vPm = (a >= 1)      ? dvdtC[k] : 0.0f;
            float bconv = (du_x + dv_y + DT_F * ((dRm - dLm) + (vCm - vPm))) * INV_DXDT;
            float pois  = lap * INV_DX2 + bconv;
            if (b < NN && a < NN) {
                cont_acc += fabsf((du_x + dv_y) * INV_DX);
                pois_acc += fabsf(pois);
            }
            ppN[k]   = ppC;          // becomes pp(a', b+1)
            vup[k]   = v1[k + 1];    // becomes v[a'][b+1]
            dvdtC[k] = dvdt[k];
        }
        #pragma unroll
        for (int j = 0; j < 5; ++j) { fnuC[j] = FNu1[j]; if (j >= 1) fnvC[j] = FNv1[j]; }
        #pragma unroll
        for (int j = 0; j < 6; ++j) { u1[j] = u2[j]; v1[j] = v2[j]; p1[j] = p2[j]; pn1[j] = pn2[j]; }
    }

    // ---- wave + block reduction, one atomic per block ----
    float c = cont_acc, q = pois_acc;
    #pragma unroll
    for (int off = 32; off > 0; off >>= 1) {
        c += __shfl_down(c, off, 64);
        q += __shfl_down(q, off, 64);
    }
    __shared__ float sred[8];
    if (lane == 0) { sred[w] = c; sred[4 + w] = q; }
    __syncthreads();
    if (threadIdx.x == 0) {
        atomicAdd(&ws[0], sred[0] + sred[1] + sred[2] + sred[3]);
        atomicAdd(&ws[1], sred[4] + sred[5] + sred[6] + sred[7]);
    }
}

// -------------------- boundary-condition partial sums --------------------
// Signed per-batch edge sums accumulate into ws[4 + 4*batch + role] from many
// blocks; abs() is deferred to pde_final (so no one-block-per-batch limit).
__global__ __launch_bounds__(256) void pde_bc(const float* __restrict__ g,
                                              float* __restrict__ ws) {
    const int bb    = blockIdx.y;
    const int slice = blockIdx.x;          // 0..7
    const int lane  = threadIdx.x & 63;
    const int role  = threadIdx.x >> 6;    // 0:y0 1:yL 2:x0 3:xL (one wave each)
    const int j     = slice * 64 + lane;   // 0..511

    const float* u = g + (size_t)bb * 3 * (CROPX * CROPX);
    const float* v = u + CROPX * CROPX;
    const float* p = v + CROPX * CROPX;

    const bool in9  = (j >= 1 && j <= NN - 1);   // 1..509
    const bool in10 = (j >= 1 && j <= NN);       // 1..510

    float val = 0.0f;
    if (role == 0) {
        if (in9)  val += u[j] + u[CROPX + j];
        if (in10) val += v[j] + p[j];
    } else if (role == 1) {
        if (in9)  val += 2.0f - u[(size_t)NN * CROPX + j] - u[(size_t)(NN + 1) * CROPX + j];
        if (in10) val += v[(size_t)(NN + 1) * CROPX + j] + p[(size_t)(NN + 1) * CROPX + j];
    } else if (role == 2) {
        if (in9)  val += v[(size_t)j * CROPX] + v[(size_t)j * CROPX + 1];
        if (in10) val += u[(size_t)j * CROPX] + p[(size_t)j * CROPX];
    } else {
        if (in9)  val += v[(size_t)j * CROPX + (CROPX - 1)] + v[(size_t)j * CROPX + (CROPX - 2)];
        if (in10) val += u[(size_t)j * CROPX + (CROPX - 1)] + p[(size_t)j * CROPX + (CROPX - 1)];
    }

    #pragma unroll
    for (int off = 32; off > 0; off >>= 1) val += __shfl_down(val, off, 64);
    if (lane == 0) atomicAdd(&ws[4 + bb * 4 + role], val);
}

// -------------------- final combine --------------------
__global__ void pde_final(const float* __restrict__ ws, float* __restrict__ out) {
    const int t = threadIdx.x;   // 64 threads
    float bc = 0.0f;
    if (t < BATCHX) {
        const float* wb = ws + 4 + t * 4;
        bc = fabsf(wb[0]) + fabsf(wb[1]) + fabsf(wb[2]) + fabsf(wb[3]);
    }
    #pragma unroll
    for (int off = 32; off > 0; off >>= 1) bc += __shfl_down(bc, off, 64);
    if (t == 0) {
        const float inv = 1.0f / ((float)BATCHX * NN * NN);
        out[0] = 0.4f * (ws[0] + ws[1]) * inv + 0.2f * bc;
    }
}

extern "C" void kernel_launch(void* const* d_in, const int* in_sizes, int n_in,
                              void* d_out, int out_size, void* d_ws, size_t ws_size,
                              hipStream_t stream) {
    const float* g  = (const float*)d_in[0];   // gen_output (32,3,512,512) f32
    const float* pn = (const float*)d_in[1];   // p_next_step (32,1,512,512) f32
    float* out = (float*)d_out;
    float* ws  = (float*)d_ws;

    hipMemsetAsync(ws, 0, (4 + BATCHX * 4) * sizeof(float), stream);

    dim3 gm(2, 16, 32);   // colgroup, supertile(4 waves of 8-row tiles), batch
    pde_main<<<gm, 256, 0, stream>>>(g, pn, ws);
    dim3 gb(8, 32);       // j-slice, batch
    pde_bc<<<gb, 256, 0, stream>>>(g, ws);
    pde_final<<<1, 64, 0, stream>>>(ws, out);
}

// Round 10
// 191.770 us; speedup vs baseline: 1.1395x; 1.0281x over previous
//
#include <hip/hip_runtime.h>

#define CROPX 512
#define NN 510          // CROP - 2
#define BATCHX 32

constexpr float INV_DX   = 100.0f;     // 1/DX
constexpr float DT_F     = 0.001f;
constexpr float INV_DXDT = 100000.0f;  // 1/(DX*DT)
constexpr float INV_DX2  = 10000.0f;   // 1/DX^2

__device__ __forceinline__ float4 ld4(const float* __restrict__ b, int r, int c) {
    return *reinterpret_cast<const float4*>(b + (size_t)r * CROPX + c);
}
__device__ __forceinline__ float2 ld2(const float* __restrict__ b, int r, int c) {
    return *reinterpret_cast<const float2*>(b + (size_t)r * CROPX + c);
}

// Warmup-only loader (R4-proven: direct loads, no cross-lane ops).
__device__ __forceinline__ void load_row6(const float* __restrict__ base, int r,
                                          int c0, float o[6]) {
    const float* rp = base + (size_t)r * CROPX;
    const float4 q = *reinterpret_cast<const float4*>(rp + c0);
    float h0, h1;
    if (c0 + 5 <= CROPX - 1) {
        const float2 h = *reinterpret_cast<const float2*>(rp + c0 + 4);
        h0 = h.x; h1 = h.y;
    } else {                                   // c0==508: outputs masked anyway
        h0 = rp[CROPX - 1];
        h1 = rp[CROPX - 1];
    }
    o[0] = q.x; o[1] = q.y; o[2] = q.z; o[3] = q.w; o[4] = h0; o[5] = h1;
}

// Prefetch buffer: NAMED vector registers only (no arrays through parameters;
// R5's array-macro version went to scratch). X##Ul = uLeft for row (_rw-1).
#define DECL_BUF(X) \
    float4 X##U, X##V, X##P, X##N; float2 X##Uh, X##Vh, X##Ph, X##Nh; \
    float X##Ul = 0.0f;

#define LOAD_BUF(X, ROW) { \
    const int _rw = (ROW); \
    X##U = ld4(u, _rw, c0);     X##V = ld4(v, _rw, c0); \
    X##P = ld4(p, _rw, c0);     X##N = ld4(pn, _rw, c0); \
    X##Uh = ld2(u, _rw, chalo); X##Vh = ld2(v, _rw, chalo); \
    X##Ph = ld2(p, _rw, chalo); X##Nh = ld2(pn, _rw, chalo); \
    if (edge0) X##Ul = u[(size_t)(_rw - 1) * CROPX + 255]; }

// -------------------- main interior kernel --------------------
// Wave = 64 lanes x 4 cols = 256 cols; 8-row tiles (R4 geometry). Depth-1
// software pipeline: iteration IT consumes buffer CUR (loaded last iteration)
// and issues buffer NXT for IT+1 BEFORE the heavy compute, so each load has a
// full iteration of compute between issue and use (breaks the convoy stall).
__global__ __launch_bounds__(256, 3) void pde_main(const float* __restrict__ g,
                                                   const float* __restrict__ png,
                                                   float* __restrict__ ws) {
    const int bb   = blockIdx.z;
    const int w    = threadIdx.x >> 6;
    const int lane = threadIdx.x & 63;
    const int tile = blockIdx.y * 4 + w;       // 0..63
    const int cg   = blockIdx.x;               // 0..1
    const int c0   = cg * 256 + lane * 4;      // first owned col (16B aligned)
    const int a0   = tile * 8;                 // first output row
    const int chalo = (c0 + 4 < 510) ? c0 + 4 : 510;   // halo float2 col (clamped)

    const float* u  = g + (size_t)bb * 3 * (CROPX * CROPX);
    const float* v  = u + CROPX * CROPX;
    const float* p  = v + CROPX * CROPX;
    const float* pn = png + (size_t)bb * (CROPX * CROPX);

    const bool edge0 = (cg == 1 && lane == 0);   // col 256: left col in other cg

    float u1[6], v1[6], p1[6], pn1[6];             // row r1 = a+1
    float fnuC[5], fnvC[5], dvdtC[4], ppN[4], vup[4];

    DECL_BUF(A)
    DECL_BUF(B)

    // ---- warmup: rows a0-1 (v only), a0, a0+1; prefetch row a0+2 into A ----
    {
        float ua[6], va[6], pa[6], pna[6];
        load_row6(u,  a0, c0, ua);
        load_row6(v,  a0, c0, va);
        load_row6(p,  a0, c0, pa);
        load_row6(pn, a0, c0, pna);
        load_row6(u,  a0 + 1, c0, u1);
        load_row6(v,  a0 + 1, c0, v1);
        load_row6(p,  a0 + 1, c0, p1);
        load_row6(pn, a0 + 1, c0, pn1);
        LOAD_BUF(A, a0 + 2)                       // in flight during warmup math

        #pragma unroll
        for (int j = 0; j < 5; ++j)
            fnuC[j] = 0.5f * (va[j] + va[j + 1]) * 0.5f * (ua[j] + u1[j]) - (u1[j] - ua[j]);
        #pragma unroll
        for (int j = 1; j < 5; ++j) {
            float m = 0.5f * (va[j] + v1[j]);
            fnvC[j] = m * m - (v1[j] - va[j]);
        }
        #pragma unroll
        for (int k = 0; k < 4; ++k) { ppN[k] = pna[k + 1] - pa[k + 1]; vup[k] = va[k + 1]; }

        if (a0 > 0) {
            float vm[6];
            load_row6(v, a0 - 1, c0, vm);
            float fev[5];
            #pragma unroll
            for (int j = 0; j < 5; ++j)
                fev[j] = 0.5f * (ua[j] + u1[j]) * 0.5f * (va[j] + va[j + 1]) - (va[j + 1] - va[j]);
            #pragma unroll
            for (int k = 0; k < 4; ++k) {
                float mm = 0.5f * (vm[k + 1] + va[k + 1]);
                float fnvm = mm * mm - (va[k + 1] - vm[k + 1]);
                dvdtC[k] = (-(fev[k + 1] - fev[k]) - (fnvC[k + 1] - fnvm)
                            - (p1[k + 1] - pa[k + 1])) * INV_DX;
            }
        } else {
            #pragma unroll
            for (int k = 0; k < 4; ++k) dvdtC[k] = 0.0f;
        }
    }

    float cont_acc = 0.0f, pois_acc = 0.0f;

// One iteration: issue NXT loads first (stay in flight through the compute),
// then consume CUR (compiler emits a counted vmcnt skipping the NXT group).
#define PDE_IT(IT, CUR, NXT)                                                      \
    {                                                                             \
        const int a = a0 + (IT);                                                  \
        if ((IT) < 7) LOAD_BUF(NXT, ((a + 3 < CROPX) ? a + 3 : CROPX - 1))        \
        float u2[6], v2[6], p2[6], pn2[6];                                        \
        u2[0] = CUR##U.x;  u2[1] = CUR##U.y;  u2[2] = CUR##U.z;  u2[3] = CUR##U.w;\
        u2[4] = CUR##Uh.x; u2[5] = CUR##Uh.y;                                     \
        v2[0] = CUR##V.x;  v2[1] = CUR##V.y;  v2[2] = CUR##V.z;  v2[3] = CUR##V.w;\
        v2[4] = CUR##Vh.x; v2[5] = CUR##Vh.y;                                     \
        p2[0] = CUR##P.x;  p2[1] = CUR##P.y;  p2[2] = CUR##P.z;  p2[3] = CUR##P.w;\
        p2[4] = CUR##Ph.x; p2[5] = CUR##Ph.y;                                     \
        pn2[0] = CUR##N.x;  pn2[1] = CUR##N.y;  pn2[2] = CUR##N.z;                \
        pn2[3] = CUR##N.w;  pn2[4] = CUR##Nh.x; pn2[5] = CUR##Nh.y;               \
        const float uLeft = CUR##Ul;                                              \
        float FEu[5], FEv[5], FNu1[5], FNv1[5];                                   \
        _Pragma("unroll")                                                         \
        for (int j = 0; j < 5; ++j) {                                             \
            float ux = 0.5f * (u1[j] + u1[j + 1]);                                \
            FEu[j] = ux * ux - (u1[j + 1] - u1[j]);                               \
            float uy = 0.5f * (u1[j] + u2[j]);                                    \
            float vx = 0.5f * (v1[j] + v1[j + 1]);                                \
            float prod = uy * vx;                                                 \
            FEv[j]  = prod - (v1[j + 1] - v1[j]);                                 \
            FNu1[j] = prod - (u2[j] - u1[j]);                                     \
        }                                                                         \
        _Pragma("unroll")                                                         \
        for (int j = 1; j < 5; ++j) {                                             \
            float vy = 0.5f * (v1[j] + v2[j]);                                    \
            FNv1[j] = vy * vy - (v2[j] - v1[j]);                                  \
        }                                                                         \
        float dudt[4], dvdt[4];                                                   \
        _Pragma("unroll")                                                         \
        for (int k = 0; k < 4; ++k) {                                             \
            dudt[k] = (-(FEu[k + 1] - FEu[k]) - (FNu1[k + 1] - fnuC[k + 1])       \
                       - (p1[k + 2] - p1[k + 1])) * INV_DX;                       \
            dvdt[k] = (-(FEv[k + 1] - FEv[k]) - (FNv1[k + 1] - fnvC[k + 1])       \
                       - (p2[k + 1] - p1[k + 1])) * INV_DX;                       \
        }                                                                         \
        float dudtLm = __shfl_up(dudt[3], 1, 64);                                 \
        if (edge0) {                                                              \
            float uxm  = 0.5f * (uLeft + u1[0]);                                  \
            float FEuL = uxm * uxm - (u1[0] - uLeft);                             \
            dudtLm = (-(FEu[0] - FEuL) - (FNu1[0] - fnuC[0])                      \
                      - (p1[1] - p1[0])) * INV_DX;                                \
        }                                                                         \
        _Pragma("unroll")                                                         \
        for (int k = 0; k < 4; ++k) {                                             \
            const int b = c0 + k;                                                 \
            float ppC = pn1[k + 1] - p1[k + 1];                                   \
            float ppS = pn2[k + 1] - p2[k + 1];                                   \
            float ppW = pn1[k]     - p1[k];                                       \
            float ppE = pn1[k + 2] - p1[k + 2];                                   \
            float lap = 4.0f * ppC - ppE - ppW - ppS - ppN[k];                    \
            float du_x = u1[k + 1] - u1[k];                                       \
            float dv_y = v1[k + 1] - vup[k];                                      \
            float dL  = (k == 0) ? dudtLm : dudt[k - 1];                          \
            float dRm = (b <= NN - 2) ? dudt[k] : 0.0f;                           \
            float dLm = (b >= 1)      ? dL      : 0.0f;                           \
            float vCm = (a <= NN - 2) ? dvdt[k] : 0.0f;                           \
            float vPm = (a >= 1)      ? dvdtC[k] : 0.0f;                          \
            float bconv = (du_x + dv_y + DT_F * ((dRm - dLm) + (vCm - vPm)))      \
                          * INV_DXDT;                                             \
            float pois  = lap * INV_DX2 + bconv;                                  \
            if (b < NN && a < NN) {                                               \
                cont_acc += fabsf((du_x + dv_y) * INV_DX);                        \
                pois_acc += fabsf(pois);                                          \
            }                                                                     \
            ppN[k]   = ppC;                                                       \
            vup[k]   = v1[k + 1];                                                 \
            dvdtC[k] = dvdt[k];                                                   \
        }                                                                         \
        _Pragma("unroll")                                                         \
        for (int j = 0; j < 5; ++j) { fnuC[j] = FNu1[j]; if (j >= 1) fnvC[j] = FNv1[j]; } \
        _Pragma("unroll")                                                         \
        for (int j = 0; j < 6; ++j) {                                             \
            u1[j] = u2[j]; v1[j] = v2[j]; p1[j] = p2[j]; pn1[j] = pn2[j];         \
        }                                                                         \
    }

    PDE_IT(0, A, B)
    PDE_IT(1, B, A)
    PDE_IT(2, A, B)
    PDE_IT(3, B, A)
    PDE_IT(4, A, B)
    PDE_IT(5, B, A)
    PDE_IT(6, A, B)
    PDE_IT(7, B, A)
#undef PDE_IT

    // ---- wave + block reduction, one atomic per block ----
    float c = cont_acc, q = pois_acc;
    #pragma unroll
    for (int off = 32; off > 0; off >>= 1) {
        c += __shfl_down(c, off, 64);
        q += __shfl_down(q, off, 64);
    }
    __shared__ float sred[8];
    if (lane == 0) { sred[w] = c; sred[4 + w] = q; }
    __syncthreads();
    if (threadIdx.x == 0) {
        atomicAdd(&ws[0], sred[0] + sred[1] + sred[2] + sred[3]);
        atomicAdd(&ws[1], sred[4] + sred[5] + sred[6] + sred[7]);
    }
}

// -------------------- boundary-condition partial sums --------------------
__global__ __launch_bounds__(256) void pde_bc(const float* __restrict__ g,
                                              float* __restrict__ ws) {
    const int bb    = blockIdx.y;
    const int slice = blockIdx.x;          // 0..7
    const int lane  = threadIdx.x & 63;
    const int role  = threadIdx.x >> 6;    // 0:y0 1:yL 2:x0 3:xL (one wave each)
    const int j     = slice * 64 + lane;   // 0..511

    const float* u = g + (size_t)bb * 3 * (CROPX * CROPX);
    const float* v = u + CROPX * CROPX;
    const float* p = v + CROPX * CROPX;

    const bool in9  = (j >= 1 && j <= NN - 1);   // 1..509
    const bool in10 = (j >= 1 && j <= NN);       // 1..510

    float val = 0.0f;
    if (role == 0) {
        if (in9)  val += u[j] + u[CROPX + j];
        if (in10) val += v[j] + p[j];
    } else if (role == 1) {
        if (in9)  val += 2.0f - u[(size_t)NN * CROPX + j] - u[(size_t)(NN + 1) * CROPX + j];
        if (in10) val += v[(size_t)(NN + 1) * CROPX + j] + p[(size_t)(NN + 1) * CROPX + j];
    } else if (role == 2) {
        if (in9)  val += v[(size_t)j * CROPX] + v[(size_t)j * CROPX + 1];
        if (in10) val += u[(size_t)j * CROPX] + p[(size_t)j * CROPX];
    } else {
        if (in9)  val += v[(size_t)j * CROPX + (CROPX - 1)] + v[(size_t)j * CROPX + (CROPX - 2)];
        if (in10) val += u[(size_t)j * CROPX + (CROPX - 1)] + p[(size_t)j * CROPX + (CROPX - 1)];
    }

    #pragma unroll
    for (int off = 32; off > 0; off >>= 1) val += __shfl_down(val, off, 64);
    if (lane == 0) atomicAdd(&ws[4 + bb * 4 + role], val);
}

// -------------------- final combine --------------------
__global__ void pde_final(const float* __restrict__ ws, float* __restrict__ out) {
    const int t = threadIdx.x;   // 64 threads
    float bc = 0.0f;
    if (t < BATCHX) {
        const float* wb = ws + 4 + t * 4;
        bc = fabsf(wb[0]) + fabsf(wb[1]) + fabsf(wb[2]) + fabsf(wb[3]);
    }
    #pragma unroll
    for (int off = 32; off > 0; off >>= 1) bc += __shfl_down(bc, off, 64);
    if (t == 0) {
        const float inv = 1.0f / ((float)BATCHX * NN * NN);
        out[0] = 0.4f * (ws[0] + ws[1]) * inv + 0.2f * bc;
    }
}

extern "C" void kernel_launch(void* const* d_in, const int* in_sizes, int n_in,
                              void* d_out, int out_size, void* d_ws, size_t ws_size,
                              hipStream_t stream) {
    const float* g  = (const float*)d_in[0];   // gen_output (32,3,512,512) f32
    const float* pn = (const float*)d_in[1];   // p_next_step (32,1,512,512) f32
    float* out = (float*)d_out;
    float* ws  = (float*)d_ws;

    hipMemsetAsync(ws, 0, (4 + BATCHX * 4) * sizeof(float), stream);

    dim3 gm(2, 16, 32);   // colgroup, supertile(4 waves of 8-row tiles), batch
    pde_main<<<gm, 256, 0, stream>>>(g, pn, ws);
    dim3 gb(8, 32);       // j-slice, batch
    pde_bc<<<gb, 256, 0, stream>>>(g, ws);
    pde_final<<<1, 64, 0, stream>>>(ws, out);
}